// Round 7
// baseline (1321.662 us; speedup 1.0000x reference)
//
#include <hip/hip_runtime.h>
#include <math.h>

#define BB 64
#define SS 4096
// ws layout (float offsets)
#define OF_G    0              // 2*4*256*20 = 40960 floats
#define OF_BG   40960          // 80 (scaled combined bias)
#define OF_DIST 41056          // 64*40 = 2560
#define OF_HFIN 43616          // 64*20 = 1280
#define OF_WS   44896          // 3200 (gate-scaled W_ih copy)
#define OF_X    48096          // 64*4096*80 floats + 8-step pad
#define WS_NEEDED_FLOATS (OF_X + (size_t)BB * SS * 80 + 8 * 80)

#define L2E 1.4426950408889634f

__device__ __forceinline__ float fast_rcp(float x) { return __builtin_amdgcn_rcpf(x); }
__device__ __forceinline__ float fast_exp2(float x) { return __builtin_amdgcn_exp2f(x); }
__device__ __forceinline__ float sigm_prec(float x) { return 1.0f / (1.0f + __expf(-x)); }
#define RL(v, m) __int_as_float(__builtin_amdgcn_readlane(__float_as_int(v), (m)))

// ---------------- K0: G tables + scaled bias/W_ih + zero dist -------------------
__global__ __launch_bounds__(256) void k_init(const float* __restrict__ pc_emb,
    const float* __restrict__ addr_emb, const float* __restrict__ enc_W,
    const float* __restrict__ b_ih, const float* __restrict__ b_hh,
    const float* __restrict__ W_ih, float* __restrict__ ws) {
  int gid = blockIdx.x * 256 + threadIdx.x;
  if (gid < 2048) {
    int t = gid >> 10;          // stream: 0=pc, 1=addr
    int i = (gid >> 8) & 3;     // byte position
    int byt = gid & 255;
    const float* tab = (t == 0 ? pc_emb : addr_emb) + (i * 256 + byt) * 20;
    float tv[20];
#pragma unroll
    for (int m = 0; m < 20; m++) tv[m] = tab[m];
    float* Grow = ws + OF_G + gid * 20;
#pragma unroll
    for (int j = 0; j < 20; j++) {
      float acc = 0.f;
#pragma unroll
      for (int m = 0; m < 20; m++) acc = fmaf(enc_W[j * 80 + i * 20 + m], tv[m], acc);
      Grow[j] = acc;
    }
  } else if (gid < 2048 + 80) {
    int g = gid - 2048;
    float sc = (g >= 40 && g < 60) ? (2.0f * L2E) : (-L2E);
    ws[OF_BG + g] = (b_ih[g] + b_hh[g]) * sc;
  } else if (gid < 2048 + 80 + 2560) {
    ws[OF_DIST + (gid - 2128)] = 0.f;
  } else if (gid < 2048 + 80 + 2560 + 3200) {
    int q = gid - 4688;         // flat index into W_ih (g*40+d)
    int g = q / 40;
    float sc = (g >= 40 && g < 60) ? (2.0f * L2E) : (-L2E);
    ws[OF_WS + q] = W_ih[q] * sc;
  }
}

// ---------------- K1: embed + encoder + X precompute (coalesced) + dist ---------
__global__ __launch_bounds__(64) void k_embed(const int* __restrict__ inp,
    const float* __restrict__ enc_b, float* __restrict__ ws) {
  __shared__ float lds[80 * 65];   // X-tile staged (padded); reused for e-transpose
  int b = blockIdx.x >> 6;
  int schunk = (blockIdx.x & 63) << 6;
  int t = threadIdx.x;
  int s = schunk + t;
  unsigned v0 = (unsigned)inp[(b * SS + s) * 2 + 0];
  unsigned v1 = (unsigned)inp[(b * SS + s) * 2 + 1];
  const float4* G4 = (const float4*)(ws + OF_G);
  float e[40];
#pragma unroll
  for (int st = 0; st < 2; st++) {
    unsigned v = (st == 0) ? v0 : v1;
    int by0 = (int)(v >> 24);
    int by1 = (int)((v >> 16) & 255u);
    int by2 = (int)((v >> 8) & 255u);
    int by3 = (int)(v & 255u);
    int r0 = ((st * 4 + 0) * 256 + by0) * 5;
    int r1 = ((st * 4 + 1) * 256 + by1) * 5;
    int r2 = ((st * 4 + 2) * 256 + by2) * 5;
    int r3 = ((st * 4 + 3) * 256 + by3) * 5;
    float4 acc[5];
#pragma unroll
    for (int p = 0; p < 5; p++) {
      float4 a = G4[r0 + p];
      float4 bq = G4[r1 + p];
      float4 cq = G4[r2 + p];
      float4 d = G4[r3 + p];
      acc[p] = make_float4(a.x + bq.x + cq.x + d.x, a.y + bq.y + cq.y + d.y,
                           a.z + bq.z + cq.z + d.z, a.w + bq.w + cq.w + d.w);
    }
    const float* af = (const float*)acc;
#pragma unroll
    for (int j = 0; j < 20; j++)
      e[st * 20 + j] = sigm_prec(enc_b[j] + af[j]);
  }
  const float* Wsc = ws + OF_WS;
  const float* bg = ws + OF_BG;
#pragma unroll 4
  for (int g = 0; g < 80; g++) {
    float a = bg[g];
#pragma unroll
    for (int d = 0; d < 40; d++) a = fmaf(Wsc[g * 40 + d], e[d], a);
    lds[g * 65 + t] = a;          // banks (g+t)%32: conflict-free
  }
  __syncthreads();
  float4* XF4 = (float4*)(ws + OF_X) + (size_t)(b * SS + schunk) * 20;
#pragma unroll
  for (int it = 0; it < 20; it++) {
    int q = it * 64 + t;          // 0..1279
    int tok = q / 20;
    int jf = q - tok * 20;
    float4 vv;
    vv.x = lds[(0  + jf) * 65 + tok];   // i (pre-scaled)
    vv.y = lds[(20 + jf) * 65 + tok];   // f
    vv.z = lds[(40 + jf) * 65 + tok];   // g
    vv.w = lds[(60 + jf) * 65 + tok];   // o
    XF4[q] = vv;
  }
  __syncthreads();
  float* eT = lds;                // 40*66 = 2640 <= 5200
#pragma unroll
  for (int d = 0; d < 40; d++) eT[d * 66 + t] = e[d];
  __syncthreads();
  if (t < 40) {
    float ssum = 0.f;
#pragma unroll 8
    for (int tok = 0; tok < 64; tok++) ssum += eT[t * 66 + tok];
    atomicAdd(ws + OF_DIST + b * 40 + t, ssum);
  }
}

// ---------------- K2: sequential LSTM, one wave per batch item ------------------
// Scalar-FMA 4-chain interleave: per m, one readlane (pipelined 1 ahead) feeds
// 4 independent v_fma (i,f,g,o chains) each using the SGPR operand directly —
// no v2f pair materialization, consecutive instrs always independent.
__global__ __launch_bounds__(64) void k_lstm(const float* __restrict__ h0,
    const float* __restrict__ c0, const float* __restrict__ W_hh,
    float* __restrict__ ws) {
  int b = blockIdx.x;
  int l = threadIdx.x;
  int j = (l & 31) < 20 ? (l & 31) : 19;  // lanes >=20 mirror j=19 harmlessly
  float wi[20], wf[20], wg[20], wo[20];
#pragma unroll
  for (int m = 0; m < 20; m++) {
    wi[m] = W_hh[(0 * 20 + j) * 20 + m] * (-L2E);
    wf[m] = W_hh[(1 * 20 + j) * 20 + m] * (-L2E);
    wg[m] = W_hh[(2 * 20 + j) * 20 + m] * (2.0f * L2E);
    wo[m] = W_hh[(3 * 20 + j) * 20 + m] * (-L2E);
  }
  float h = h0[b * 20 + j];
  float cs = c0[b * 20 + j] * (2.0f * L2E);   // pre-scaled cell state
  const float4* Xp = (const float4*)(ws + OF_X) + (size_t)b * SS * 20 + j;
  float4 xb[8];
#pragma unroll
  for (int p = 0; p < 8; p++) xb[p] = Xp[p * 20];
  const float4* Xq = Xp;
  for (int s = 0; s < SS; s += 8) {
#pragma unroll
    for (int u = 0; u < 8; u++) {
      float4 x4 = xb[u];
      xb[u] = Xq[(u + 8) * 20];   // constant-offset prefetch, 8 steps ahead
      float a_i = x4.x, a_f = x4.y, a_g = x4.z, a_o = x4.w;
      float hc = RL(h, 0);
#pragma unroll
      for (int m = 0; m < 20; m++) {
        float hn = (m < 19) ? RL(h, m + 1) : 0.f;  // write->use gap: 4 fmas
        a_i = fmaf(wi[m], hc, a_i);
        a_f = fmaf(wf[m], hc, a_f);
        a_g = fmaf(wg[m], hc, a_g);
        a_o = fmaf(wo[m], hc, a_o);
        hc = hn;
      }
      float si = fast_rcp(1.0f + fast_exp2(a_i));
      float sf = fast_rcp(1.0f + fast_exp2(a_f));
      // tg pre-multiplied by 2*L2E: tg2 = 2L2E - 4L2E * rcp(1+exp2(a_g))
      float tg2 = fmaf(-4.0f * L2E, fast_rcp(1.0f + fast_exp2(a_g)), 2.0f * L2E);
      float so = fast_rcp(1.0f + fast_exp2(a_o));
      cs = fmaf(sf, cs, si * tg2);
      float tc = fmaf(-2.0f, fast_rcp(1.0f + fast_exp2(cs)), 1.0f);
      h = so * tc;
    }
    Xq += 8 * 20;
  }
  if (l < 20) ws[OF_HFIN + b * 20 + l] = h;
}

// ---------------- K3: decoder heads + softmax over batch axis -------------------
__global__ __launch_bounds__(256) void k_dec(const float* __restrict__ dec_W,
    const float* __restrict__ dec_b, float* __restrict__ out,
    const float* __restrict__ ws) {
  int wid = blockIdx.x * 4 + (threadIdx.x >> 6);  // (k,v) pair id, 0..1023
  int lane = threadIdx.x & 63;                    // = batch index b
  int k = wid >> 8;
  int v = wid & 255;
  const float* hp = ws + OF_HFIN + lane * 20;
  const float* wp = dec_W + (k * 256 + v) * 20;
  float l = dec_b[k * 256 + v];
#pragma unroll
  for (int jj = 0; jj < 20; jj++) l = fmaf(hp[jj], wp[jj], l);
  float x = l / 0.001f;
  float mx = x;
#pragma unroll
  for (int off = 32; off; off >>= 1) mx = fmaxf(mx, __shfl_xor(mx, off));
  float ex = __expf(x - mx);
  float sm = ex;
#pragma unroll
  for (int off = 32; off; off >>= 1) sm += __shfl_xor(sm, off);
  float p = ex / sm;
  int oidx = (k * 64 + lane) * 256 + v;
  out[oidx] = p;            // probs
  out[65536 + oidx] = l;    // logits
}

// ---------------- K4: byte_e = probs @ addr_emb, encoder, MLP head --------------
__global__ __launch_bounds__(128) void k_freq(const float* __restrict__ addr_emb,
    const float* __restrict__ enc_W, const float* __restrict__ enc_b,
    const float* __restrict__ d1_W, const float* __restrict__ d1_b,
    const float* __restrict__ d2_W, const float* __restrict__ d2_b,
    float* __restrict__ out, const float* __restrict__ ws) {
  __shared__ float be[80];
  __shared__ float fr[60];
  __shared__ float r1[10];
  int b = blockIdx.x;
  int t = threadIdx.x;
  if (t < 80) {
    int k = t / 20, e2 = t % 20;
    const float* pp = out + (k * 64 + b) * 256;        // probs[k,0,b,:]
    const float* ap = addr_emb + (k * 256) * 20 + e2;
    float acc = 0.f;
#pragma unroll 8
    for (int v = 0; v < 256; v++) acc = fmaf(pp[v], ap[v * 20], acc);
    be[t] = acc;   // byte_e[b][k][e2], flat k*20+e2
  }
  __syncthreads();
  if (t < 20) {
    float acc = enc_b[t];
#pragma unroll
    for (int d = 0; d < 80; d++) acc = fmaf(enc_W[t * 80 + d], be[d], acc);
    fr[t] = 1.0f / (1.0f + __expf(-acc));              // fe
  } else if (t < 60) {
    fr[t] = ws[OF_DIST + b * 40 + (t - 20)] * (1.0f / 4096.0f);  // dist_vector
  }
  __syncthreads();
  if (t < 10) {
    float acc = d1_b[t];
#pragma unroll
    for (int d = 0; d < 60; d++) acc = fmaf(d1_W[t * 60 + d], fr[d], acc);
    r1[t] = acc > 0.f ? acc : 0.f;
  }
  __syncthreads();
  if (t < 2) {
    float acc = d2_b[t];
#pragma unroll
    for (int r = 0; r < 10; r++) acc = fmaf(d2_W[t * 10 + r], r1[r], acc);
    out[131072 + t * 64 + b] = acc;
  }
}

extern "C" void kernel_launch(void* const* d_in, const int* in_sizes, int n_in,
                              void* d_out, int out_size, void* d_ws, size_t ws_size,
                              hipStream_t stream) {
  const int*   inp    = (const int*)  d_in[0];
  const float* h0     = (const float*)d_in[1];
  const float* c0     = (const float*)d_in[2];
  const float* pc_emb = (const float*)d_in[3];
  const float* addr_e = (const float*)d_in[4];
  const float* enc_W  = (const float*)d_in[5];
  const float* enc_b  = (const float*)d_in[6];
  const float* W_ih   = (const float*)d_in[7];
  const float* W_hh   = (const float*)d_in[8];
  const float* b_ih   = (const float*)d_in[9];
  const float* b_hh   = (const float*)d_in[10];
  const float* dec_W  = (const float*)d_in[11];
  const float* dec_b  = (const float*)d_in[12];
  const float* d1_W   = (const float*)d_in[13];
  const float* d1_b   = (const float*)d_in[14];
  const float* d2_W   = (const float*)d_in[15];
  const float* d2_b   = (const float*)d_in[16];
  float* out = (float*)d_out;
  float* ws  = (float*)d_ws;

  if (ws_size < WS_NEEDED_FLOATS * sizeof(float)) return;

  hipLaunchKernelGGL(k_init, dim3(31), dim3(256), 0, stream,
                     pc_emb, addr_e, enc_W, b_ih, b_hh, W_ih, ws);
  hipLaunchKernelGGL(k_embed, dim3(4096), dim3(64), 0, stream, inp, enc_b, ws);
  hipLaunchKernelGGL(k_lstm, dim3(64), dim3(64), 0, stream, h0, c0, W_hh, ws);
  hipLaunchKernelGGL(k_dec, dim3(256), dim3(256), 0, stream, dec_W, dec_b, out, ws);
  hipLaunchKernelGGL(k_freq, dim3(64), dim3(128), 0, stream,
                     addr_e, enc_W, enc_b, d1_W, d1_b, d2_W, d2_b, out, ws);
}

// Round 8
// 866.999 us; speedup vs baseline: 1.5244x; 1.5244x over previous
//
#include <hip/hip_runtime.h>
#include <math.h>

#define BB 64
#define SS 4096
// ws layout (float offsets)
#define OF_G    0              // 2*4*256*20 = 40960 floats
#define OF_BG   40960          // 80 (scaled combined bias)
#define OF_DIST 41056          // 64*40 = 2560
#define OF_HFIN 43616          // 64*20 = 1280
#define OF_WS   44896          // 3200 (gate-scaled W_ih copy)
#define OF_X    48096          // 64*4096*80 floats + 8-step pad
#define WS_NEEDED_FLOATS (OF_X + (size_t)BB * SS * 80 + 8 * 80)

#define L2E 1.4426950408889634f

typedef float v2f __attribute__((ext_vector_type(2)));

__device__ __forceinline__ float fast_rcp(float x) { return __builtin_amdgcn_rcpf(x); }
__device__ __forceinline__ float fast_exp2(float x) { return __builtin_amdgcn_exp2f(x); }
__device__ __forceinline__ float sigm_prec(float x) { return 1.0f / (1.0f + __expf(-x)); }
#define RL(v, m) __int_as_float(__builtin_amdgcn_readlane(__float_as_int(v), (m)))

// ---------------- K0: G tables + scaled bias/W_ih + zero dist -------------------
__global__ __launch_bounds__(256) void k_init(const float* __restrict__ pc_emb,
    const float* __restrict__ addr_emb, const float* __restrict__ enc_W,
    const float* __restrict__ b_ih, const float* __restrict__ b_hh,
    const float* __restrict__ W_ih, float* __restrict__ ws) {
  int gid = blockIdx.x * 256 + threadIdx.x;
  if (gid < 2048) {
    int t = gid >> 10;          // stream: 0=pc, 1=addr
    int i = (gid >> 8) & 3;     // byte position
    int byt = gid & 255;
    const float* tab = (t == 0 ? pc_emb : addr_emb) + (i * 256 + byt) * 20;
    float tv[20];
#pragma unroll
    for (int m = 0; m < 20; m++) tv[m] = tab[m];
    float* Grow = ws + OF_G + gid * 20;
#pragma unroll
    for (int j = 0; j < 20; j++) {
      float acc = 0.f;
#pragma unroll
      for (int m = 0; m < 20; m++) acc = fmaf(enc_W[j * 80 + i * 20 + m], tv[m], acc);
      Grow[j] = acc;
    }
  } else if (gid < 2048 + 80) {
    int g = gid - 2048;
    float sc = (g >= 40 && g < 60) ? (2.0f * L2E) : (-L2E);
    ws[OF_BG + g] = (b_ih[g] + b_hh[g]) * sc;
  } else if (gid < 2048 + 80 + 2560) {
    ws[OF_DIST + (gid - 2128)] = 0.f;
  } else if (gid < 2048 + 80 + 2560 + 3200) {
    int q = gid - 4688;         // flat index into W_ih (g*40+d)
    int g = q / 40;
    float sc = (g >= 40 && g < 60) ? (2.0f * L2E) : (-L2E);
    ws[OF_WS + q] = W_ih[q] * sc;
  }
}

// ---------------- K1: embed + encoder + X precompute (coalesced) + dist ---------
__global__ __launch_bounds__(64) void k_embed(const int* __restrict__ inp,
    const float* __restrict__ enc_b, float* __restrict__ ws) {
  __shared__ float lds[80 * 65];   // X-tile staged (padded); reused for e-transpose
  int b = blockIdx.x >> 6;
  int schunk = (blockIdx.x & 63) << 6;
  int t = threadIdx.x;
  int s = schunk + t;
  unsigned v0 = (unsigned)inp[(b * SS + s) * 2 + 0];
  unsigned v1 = (unsigned)inp[(b * SS + s) * 2 + 1];
  const float4* G4 = (const float4*)(ws + OF_G);
  float e[40];
#pragma unroll
  for (int st = 0; st < 2; st++) {
    unsigned v = (st == 0) ? v0 : v1;
    int by0 = (int)(v >> 24);
    int by1 = (int)((v >> 16) & 255u);
    int by2 = (int)((v >> 8) & 255u);
    int by3 = (int)(v & 255u);
    int r0 = ((st * 4 + 0) * 256 + by0) * 5;
    int r1 = ((st * 4 + 1) * 256 + by1) * 5;
    int r2 = ((st * 4 + 2) * 256 + by2) * 5;
    int r3 = ((st * 4 + 3) * 256 + by3) * 5;
    float4 acc[5];
#pragma unroll
    for (int p = 0; p < 5; p++) {
      float4 a = G4[r0 + p];
      float4 bq = G4[r1 + p];
      float4 cq = G4[r2 + p];
      float4 d = G4[r3 + p];
      acc[p] = make_float4(a.x + bq.x + cq.x + d.x, a.y + bq.y + cq.y + d.y,
                           a.z + bq.z + cq.z + d.z, a.w + bq.w + cq.w + d.w);
    }
    const float* af = (const float*)acc;
#pragma unroll
    for (int j = 0; j < 20; j++)
      e[st * 20 + j] = sigm_prec(enc_b[j] + af[j]);
  }
  const float* Wsc = ws + OF_WS;
  const float* bg = ws + OF_BG;
#pragma unroll 4
  for (int g = 0; g < 80; g++) {
    float a = bg[g];
#pragma unroll
    for (int d = 0; d < 40; d++) a = fmaf(Wsc[g * 40 + d], e[d], a);
    lds[g * 65 + t] = a;          // banks (g+t)%32: conflict-free
  }
  __syncthreads();
  float4* XF4 = (float4*)(ws + OF_X) + (size_t)(b * SS + schunk) * 20;
#pragma unroll
  for (int it = 0; it < 20; it++) {
    int q = it * 64 + t;          // 0..1279
    int tok = q / 20;
    int jf = q - tok * 20;
    float4 vv;
    vv.x = lds[(0  + jf) * 65 + tok];   // i (pre-scaled)
    vv.y = lds[(20 + jf) * 65 + tok];   // f
    vv.z = lds[(40 + jf) * 65 + tok];   // g
    vv.w = lds[(60 + jf) * 65 + tok];   // o
    XF4[q] = vv;
  }
  __syncthreads();
  float* eT = lds;                // 40*66 = 2640 <= 5200
#pragma unroll
  for (int d = 0; d < 40; d++) eT[d * 66 + t] = e[d];
  __syncthreads();
  if (t < 40) {
    float ssum = 0.f;
#pragma unroll 8
    for (int tok = 0; tok < 64; tok++) ssum += eT[t * 66 + tok];
    atomicAdd(ws + OF_DIST + b * 40 + t, ssum);
  }
}

// ---------------- K2: sequential LSTM, one wave per batch item ------------------
// Gate-split across wave halves: one half computes the (i,f) pk-pair, the other
// (g,o) — shared instruction stream, lane-private weights => 20 pk_fma + shared
// activations. Cross-half exchange via gfx950 v_permlane32_swap_b32 (VALU pipe).
// A one-time probe resolves the swap direction; sp = (l>>5)^dir makes either
// hardware convention correct at zero per-step cost.
__global__ __launch_bounds__(64) void k_lstm(const float* __restrict__ h0,
    const float* __restrict__ c0, const float* __restrict__ W_hh,
    float* __restrict__ ws) {
  int b = blockIdx.x;
  int l = threadIdx.x;
  int j = (l & 31) < 20 ? (l & 31) : 19;  // lanes >=20 mirror j=19 harmlessly
  // --- direction probe: which half-origin ends up in the vdst operand? ---
  float q0 = (float)l, q1 = (float)l;
  asm("v_permlane32_swap_b32 %0, %1" : "+v"(q0), "+v"(q1));
  int dir = (__builtin_amdgcn_readfirstlane(__float_as_int(q0)) == 0) ? 0 : 1;
  int sp = ((l >> 5) ^ dir) & 1;   // sp==0: this lane computes (i,f); sp==1: (g,o)
  v2f wAB[20];
#pragma unroll
  for (int m = 0; m < 20; m++) {
    float wa = (sp == 0) ? W_hh[(0 * 20 + j) * 20 + m] * (-L2E)
                         : W_hh[(2 * 20 + j) * 20 + m] * (2.0f * L2E);
    float wb = (sp == 0) ? W_hh[(1 * 20 + j) * 20 + m] * (-L2E)
                         : W_hh[(3 * 20 + j) * 20 + m] * (-L2E);
    wAB[m] = (v2f){wa, wb};
  }
  // post-rcp transform constants: (i,f)/(o): identity; (g): tg2 = 2L2E - 4L2E*r
  v2f kA = (sp == 0) ? (v2f){1.0f, 1.0f} : (v2f){-4.0f * L2E, 1.0f};
  v2f kB = (sp == 0) ? (v2f){0.0f, 0.0f} : (v2f){2.0f * L2E, 0.0f};
  float h = h0[b * 20 + j];
  float cs = c0[b * 20 + j] * (2.0f * L2E);   // pre-scaled cell state
  // per-lane float2: (x_i,x_f) for sp==0, (x_g,x_o) for sp==1
  const float2* Xp = (const float2*)(ws + OF_X) + (size_t)b * SS * 40 + j * 2 + sp;
  float2 xb[8];
#pragma unroll
  for (int p = 0; p < 8; p++) xb[p] = Xp[p * 40];
  const float2* Xq = Xp;
  for (int s = 0; s < SS; s += 8) {
#pragma unroll
    for (int u = 0; u < 8; u++) {
      float2 x2 = xb[u];
      xb[u] = Xq[(u + 8) * 40];   // constant-offset prefetch, 8 steps ahead
      float hm[20];
#pragma unroll
      for (int m = 0; m < 4; m++) hm[m] = RL(h, m);
      v2f aA = (v2f){x2.x, x2.y};
      v2f aB = (v2f){0.f, 0.f};
#pragma unroll
      for (int m = 0; m < 10; m++) {
        hm[m + 4] = RL(h, m + 4);                 // fills 4..13
        v2f hv = (v2f){hm[m], hm[m]};
        aA = __builtin_elementwise_fma(wAB[m], hv, aA);
      }
#pragma unroll
      for (int m = 10; m < 20; m++) {
        if (m + 4 < 20) hm[m + 4] = RL(h, m + 4); // fills 14..19
        v2f hv = (v2f){hm[m], hm[m]};
        aB = __builtin_elementwise_fma(wAB[m], hv, aB);
      }
      v2f a = aA + aB;
      float e0 = fast_exp2(a.x);
      float e1 = fast_exp2(a.y);
      v2f den = (v2f){1.0f + e0, 1.0f + e1};
      v2f r = (v2f){fast_rcp(den.x), fast_rcp(den.y)};
      v2f res = __builtin_elementwise_fma(r, kA, kB);
      // cross-half exchange: d* ends holding the (si,sf)-origin pair in ALL
      // lanes, s* the (tg2,so) pair (guaranteed by the dir-probe sp mapping).
      float d0 = res.x, s0 = res.x;
      float d1 = res.y, s1 = res.y;
      asm("v_permlane32_swap_b32 %0, %1" : "+v"(d0), "+v"(s0));
      asm("v_permlane32_swap_b32 %0, %1" : "+v"(d1), "+v"(s1));
      // d0=si, d1=sf, s0=tg2(=2L2E*tanh(g)), s1=so
      cs = fmaf(d1, cs, d0 * s0);
      float tc = fmaf(-2.0f, fast_rcp(1.0f + fast_exp2(cs)), 1.0f);
      h = s1 * tc;
    }
    Xq += 8 * 40;
  }
  if (l < 20) ws[OF_HFIN + b * 20 + l] = h;
}

// ---------------- K3: decoder heads + softmax over batch axis -------------------
__global__ __launch_bounds__(256) void k_dec(const float* __restrict__ dec_W,
    const float* __restrict__ dec_b, float* __restrict__ out,
    const float* __restrict__ ws) {
  int wid = blockIdx.x * 4 + (threadIdx.x >> 6);  // (k,v) pair id, 0..1023
  int lane = threadIdx.x & 63;                    // = batch index b
  int k = wid >> 8;
  int v = wid & 255;
  const float* hp = ws + OF_HFIN + lane * 20;
  const float* wp = dec_W + (k * 256 + v) * 20;
  float l = dec_b[k * 256 + v];
#pragma unroll
  for (int jj = 0; jj < 20; jj++) l = fmaf(hp[jj], wp[jj], l);
  float x = l / 0.001f;
  float mx = x;
#pragma unroll
  for (int off = 32; off; off >>= 1) mx = fmaxf(mx, __shfl_xor(mx, off));
  float ex = __expf(x - mx);
  float sm = ex;
#pragma unroll
  for (int off = 32; off; off >>= 1) sm += __shfl_xor(sm, off);
  float p = ex / sm;
  int oidx = (k * 64 + lane) * 256 + v;
  out[oidx] = p;            // probs
  out[65536 + oidx] = l;    // logits
}

// ---------------- K4: byte_e = probs @ addr_emb, encoder, MLP head --------------
__global__ __launch_bounds__(128) void k_freq(const float* __restrict__ addr_emb,
    const float* __restrict__ enc_W, const float* __restrict__ enc_b,
    const float* __restrict__ d1_W, const float* __restrict__ d1_b,
    const float* __restrict__ d2_W, const float* __restrict__ d2_b,
    float* __restrict__ out, const float* __restrict__ ws) {
  __shared__ float be[80];
  __shared__ float fr[60];
  __shared__ float r1[10];
  int b = blockIdx.x;
  int t = threadIdx.x;
  if (t < 80) {
    int k = t / 20, e2 = t % 20;
    const float* pp = out + (k * 64 + b) * 256;        // probs[k,0,b,:]
    const float* ap = addr_emb + (k * 256) * 20 + e2;
    float acc = 0.f;
#pragma unroll 8
    for (int v = 0; v < 256; v++) acc = fmaf(pp[v], ap[v * 20], acc);
    be[t] = acc;   // byte_e[b][k][e2], flat k*20+e2
  }
  __syncthreads();
  if (t < 20) {
    float acc = enc_b[t];
#pragma unroll
    for (int d = 0; d < 80; d++) acc = fmaf(enc_W[t * 80 + d], be[d], acc);
    fr[t] = 1.0f / (1.0f + __expf(-acc));              // fe
  } else if (t < 60) {
    fr[t] = ws[OF_DIST + b * 40 + (t - 20)] * (1.0f / 4096.0f);  // dist_vector
  }
  __syncthreads();
  if (t < 10) {
    float acc = d1_b[t];
#pragma unroll
    for (int d = 0; d < 60; d++) acc = fmaf(d1_W[t * 60 + d], fr[d], acc);
    r1[t] = acc > 0.f ? acc : 0.f;
  }
  __syncthreads();
  if (t < 2) {
    float acc = d2_b[t];
#pragma unroll
    for (int r = 0; r < 10; r++) acc = fmaf(d2_W[t * 10 + r], r1[r], acc);
    out[131072 + t * 64 + b] = acc;
  }
}

extern "C" void kernel_launch(void* const* d_in, const int* in_sizes, int n_in,
                              void* d_out, int out_size, void* d_ws, size_t ws_size,
                              hipStream_t stream) {
  const int*   inp    = (const int*)  d_in[0];
  const float* h0     = (const float*)d_in[1];
  const float* c0     = (const float*)d_in[2];
  const float* pc_emb = (const float*)d_in[3];
  const float* addr_e = (const float*)d_in[4];
  const float* enc_W  = (const float*)d_in[5];
  const float* enc_b  = (const float*)d_in[6];
  const float* W_ih   = (const float*)d_in[7];
  const float* W_hh   = (const float*)d_in[8];
  const float* b_ih   = (const float*)d_in[9];
  const float* b_hh   = (const float*)d_in[10];
  const float* dec_W  = (const float*)d_in[11];
  const float* dec_b  = (const float*)d_in[12];
  const float* d1_W   = (const float*)d_in[13];
  const float* d1_b   = (const float*)d_in[14];
  const float* d2_W   = (const float*)d_in[15];
  const float* d2_b   = (const float*)d_in[16];
  float* out = (float*)d_out;
  float* ws  = (float*)d_ws;

  if (ws_size < WS_NEEDED_FLOATS * sizeof(float)) return;

  hipLaunchKernelGGL(k_init, dim3(31), dim3(256), 0, stream,
                     pc_emb, addr_e, enc_W, b_ih, b_hh, W_ih, ws);
  hipLaunchKernelGGL(k_embed, dim3(4096), dim3(64), 0, stream, inp, enc_b, ws);
  hipLaunchKernelGGL(k_lstm, dim3(64), dim3(64), 0, stream, h0, c0, W_hh, ws);
  hipLaunchKernelGGL(k_dec, dim3(256), dim3(256), 0, stream, dec_W, dec_b, out, ws);
  hipLaunchKernelGGL(k_freq, dim3(64), dim3(128), 0, stream,
                     addr_e, enc_W, enc_b, d1_W, d1_b, d2_W, d2_b, out, ws);
}

// Round 9
// 846.756 us; speedup vs baseline: 1.5609x; 1.0239x over previous
//
#include <hip/hip_runtime.h>
#include <math.h>

#define BB 64
#define SS 4096
// ws layout (float offsets)
#define OF_G    0              // 2*4*256*20 = 40960 floats
#define OF_BG   40960          // 80 (scaled combined bias)
#define OF_DIST 41056          // 64*40 = 2560
#define OF_HFIN 43616          // 64*20 = 1280
#define OF_WS   44896          // 3200 (gate-scaled W_ih copy)
#define OF_X    48096          // 64*4096*80 floats + 16-step pad (float4 prefetch)
#define WS_NEEDED_FLOATS (OF_X + (size_t)BB * SS * 80 + 16 * 80)

#define L2E 1.4426950408889634f

typedef float v2f __attribute__((ext_vector_type(2)));

__device__ __forceinline__ float fast_rcp(float x) { return __builtin_amdgcn_rcpf(x); }
__device__ __forceinline__ float fast_exp2(float x) { return __builtin_amdgcn_exp2f(x); }
__device__ __forceinline__ float sigm_prec(float x) { return 1.0f / (1.0f + __expf(-x)); }
#define RL(v, m) __int_as_float(__builtin_amdgcn_readlane(__float_as_int(v), (m)))

// ---------------- K0: G tables + scaled bias/W_ih + zero dist -------------------
__global__ __launch_bounds__(256) void k_init(const float* __restrict__ pc_emb,
    const float* __restrict__ addr_emb, const float* __restrict__ enc_W,
    const float* __restrict__ b_ih, const float* __restrict__ b_hh,
    const float* __restrict__ W_ih, float* __restrict__ ws) {
  int gid = blockIdx.x * 256 + threadIdx.x;
  if (gid < 2048) {
    int t = gid >> 10;          // stream: 0=pc, 1=addr
    int i = (gid >> 8) & 3;     // byte position
    int byt = gid & 255;
    const float* tab = (t == 0 ? pc_emb : addr_emb) + (i * 256 + byt) * 20;
    float tv[20];
#pragma unroll
    for (int m = 0; m < 20; m++) tv[m] = tab[m];
    float* Grow = ws + OF_G + gid * 20;
#pragma unroll
    for (int j = 0; j < 20; j++) {
      float acc = 0.f;
#pragma unroll
      for (int m = 0; m < 20; m++) acc = fmaf(enc_W[j * 80 + i * 20 + m], tv[m], acc);
      Grow[j] = acc;
    }
  } else if (gid < 2048 + 80) {
    int g = gid - 2048;
    float sc = (g >= 40 && g < 60) ? (2.0f * L2E) : (-L2E);
    ws[OF_BG + g] = (b_ih[g] + b_hh[g]) * sc;
  } else if (gid < 2048 + 80 + 2560) {
    ws[OF_DIST + (gid - 2128)] = 0.f;
  } else if (gid < 2048 + 80 + 2560 + 3200) {
    int q = gid - 4688;         // flat index into W_ih (g*40+d)
    int g = q / 40;
    float sc = (g >= 40 && g < 60) ? (2.0f * L2E) : (-L2E);
    ws[OF_WS + q] = W_ih[q] * sc;
  }
}

// ---------------- K1: embed + encoder + X precompute (coalesced) + dist ---------
// X stored as step-PAIR float4s: global float4 index
//   ((b*2048 + pair)*40 + (j*2+sp))  ->  (xA_g0, xA_g1, xB_g0, xB_g1)
// where g0 = sp*40+j, g1 = g0+20, steps (2*pair, 2*pair+1). One dwordx4 feeds
// TWO LSTM steps for lane (j,sp).
__global__ __launch_bounds__(64) void k_embed(const int* __restrict__ inp,
    const float* __restrict__ enc_b, float* __restrict__ ws) {
  __shared__ float lds[80 * 65];   // X-tile staged (padded); reused for e-transpose
  int b = blockIdx.x >> 6;
  int schunk = (blockIdx.x & 63) << 6;
  int t = threadIdx.x;
  int s = schunk + t;
  unsigned v0 = (unsigned)inp[(b * SS + s) * 2 + 0];
  unsigned v1 = (unsigned)inp[(b * SS + s) * 2 + 1];
  const float4* G4 = (const float4*)(ws + OF_G);
  float e[40];
#pragma unroll
  for (int st = 0; st < 2; st++) {
    unsigned v = (st == 0) ? v0 : v1;
    int by0 = (int)(v >> 24);
    int by1 = (int)((v >> 16) & 255u);
    int by2 = (int)((v >> 8) & 255u);
    int by3 = (int)(v & 255u);
    int r0 = ((st * 4 + 0) * 256 + by0) * 5;
    int r1 = ((st * 4 + 1) * 256 + by1) * 5;
    int r2 = ((st * 4 + 2) * 256 + by2) * 5;
    int r3 = ((st * 4 + 3) * 256 + by3) * 5;
    float4 acc[5];
#pragma unroll
    for (int p = 0; p < 5; p++) {
      float4 a = G4[r0 + p];
      float4 bq = G4[r1 + p];
      float4 cq = G4[r2 + p];
      float4 d = G4[r3 + p];
      acc[p] = make_float4(a.x + bq.x + cq.x + d.x, a.y + bq.y + cq.y + d.y,
                           a.z + bq.z + cq.z + d.z, a.w + bq.w + cq.w + d.w);
    }
    const float* af = (const float*)acc;
#pragma unroll
    for (int j = 0; j < 20; j++)
      e[st * 20 + j] = sigm_prec(enc_b[j] + af[j]);
  }
  const float* Wsc = ws + OF_WS;
  const float* bg = ws + OF_BG;
#pragma unroll 4
  for (int g = 0; g < 80; g++) {
    float a = bg[g];
#pragma unroll
    for (int d = 0; d < 40; d++) a = fmaf(Wsc[g * 40 + d], e[d], a);
    lds[g * 65 + t] = a;          // banks (g+t)%32: conflict-free
  }
  __syncthreads();
  // coalesced float4 flush in step-pair layout
  float4* XF4 = (float4*)(ws + OF_X) + ((size_t)b * 2048 + (schunk >> 1)) * 40;
#pragma unroll
  for (int it = 0; it < 20; it++) {
    int q = it * 64 + t;          // 0..1279 = 32 pairs * 40 lane-slots
    int lp = q / 40;              // local pair 0..31
    int lanepos = q - lp * 40;    // 0..39 = j*2+sp
    int j = lanepos >> 1;
    int sp = lanepos & 1;
    int g0 = sp * 40 + j;
    int g1 = g0 + 20;
    int tok0 = lp * 2, tok1 = tok0 + 1;
    float4 vv;
    vv.x = lds[g0 * 65 + tok0];
    vv.y = lds[g1 * 65 + tok0];
    vv.z = lds[g0 * 65 + tok1];
    vv.w = lds[g1 * 65 + tok1];
    XF4[q] = vv;
  }
  __syncthreads();
  float* eT = lds;                // 40*66 = 2640 <= 5200
#pragma unroll
  for (int d = 0; d < 40; d++) eT[d * 66 + t] = e[d];
  __syncthreads();
  if (t < 40) {
    float ssum = 0.f;
#pragma unroll 8
    for (int tok = 0; tok < 64; tok++) ssum += eT[t * 66 + tok];
    atomicAdd(ws + OF_DIST + b * 40 + t, ssum);
  }
}

// ---------------- K2: sequential LSTM, one wave per batch item ------------------
// Gate-split across wave halves (R7 structure) + 2-steps-per-float4 X loads.
// Per step: 20 RL + 20 pk_fma + trans tail; ~55 instr @ ~4.5 cyc single-wave
// issue cadence + ~100 cyc trans-chain exposure.
#define LSTM_STEP(xA, xB) do {                                                 \
    float hc = RL(h, 0);                                                       \
    v2f aA = (v2f){(xA), (xB)};                                                \
    v2f aB = (v2f){0.f, 0.f};                                                  \
    _Pragma("unroll")                                                          \
    for (int m = 0; m < 10; m++) {                                             \
      float hn = RL(h, m + 1);                                                 \
      v2f hv = (v2f){hc, hc};                                                  \
      aA = __builtin_elementwise_fma(wAB[m], hv, aA);                          \
      hc = hn;                                                                 \
    }                                                                          \
    _Pragma("unroll")                                                          \
    for (int m = 10; m < 20; m++) {                                            \
      float hn = (m < 19) ? RL(h, m + 1) : 0.f;                                \
      v2f hv = (v2f){hc, hc};                                                  \
      aB = __builtin_elementwise_fma(wAB[m], hv, aB);                          \
      hc = hn;                                                                 \
    }                                                                          \
    v2f a = aA + aB;                                                           \
    float e0 = fast_exp2(a.x);                                                 \
    float e1 = fast_exp2(a.y);                                                 \
    v2f r = (v2f){fast_rcp(1.0f + e0), fast_rcp(1.0f + e1)};                   \
    v2f res = __builtin_elementwise_fma(r, kA, kB);                            \
    float d0 = res.x, s0 = res.x;                                              \
    float d1 = res.y, s1 = res.y;                                              \
    asm("v_permlane32_swap_b32 %0, %1" : "+v"(d0), "+v"(s0));                  \
    asm("v_permlane32_swap_b32 %0, %1" : "+v"(d1), "+v"(s1));                  \
    cs = fmaf(d1, cs, d0 * s0);                                                \
    float tc = fmaf(-2.0f, fast_rcp(1.0f + fast_exp2(cs)), 1.0f);              \
    h = s1 * tc;                                                               \
  } while (0)

__global__ __launch_bounds__(64) void k_lstm(const float* __restrict__ h0,
    const float* __restrict__ c0, const float* __restrict__ W_hh,
    float* __restrict__ ws) {
  int b = blockIdx.x;
  int l = threadIdx.x;
  int j = (l & 31) < 20 ? (l & 31) : 19;  // lanes >=20 mirror j=19 harmlessly
  // --- direction probe: which half-origin ends up in the vdst operand? ---
  float q0 = (float)l, q1 = (float)l;
  asm("v_permlane32_swap_b32 %0, %1" : "+v"(q0), "+v"(q1));
  int dir = (__builtin_amdgcn_readfirstlane(__float_as_int(q0)) == 0) ? 0 : 1;
  int sp = ((l >> 5) ^ dir) & 1;   // sp==0: this lane computes (i,f); sp==1: (g,o)
  v2f wAB[20];
#pragma unroll
  for (int m = 0; m < 20; m++) {
    float wa = (sp == 0) ? W_hh[(0 * 20 + j) * 20 + m] * (-L2E)
                         : W_hh[(2 * 20 + j) * 20 + m] * (2.0f * L2E);
    float wb = (sp == 0) ? W_hh[(1 * 20 + j) * 20 + m] * (-L2E)
                         : W_hh[(3 * 20 + j) * 20 + m] * (-L2E);
    wAB[m] = (v2f){wa, wb};
  }
  // post-rcp transform constants: (i,f)/(o): identity; (g): tg2 = 2L2E - 4L2E*r
  v2f kA = (sp == 0) ? (v2f){1.0f, 1.0f} : (v2f){-4.0f * L2E, 1.0f};
  v2f kB = (sp == 0) ? (v2f){0.0f, 0.0f} : (v2f){2.0f * L2E, 0.0f};
  float h = h0[b * 20 + j];
  float cs = c0[b * 20 + j] * (2.0f * L2E);   // pre-scaled cell state
  // per-lane float4 = 2 steps: (xA_a, xA_b, xB_a, xB_b)
  const float4* Xp = (const float4*)(ws + OF_X) + (size_t)b * 2048 * 40 + (j * 2 + sp);
  float4 xb[8];
#pragma unroll
  for (int p = 0; p < 8; p++) xb[p] = Xp[p * 40];
  const float4* Xq = Xp;
  for (int pr = 0; pr < 2048; pr += 8) {
#pragma unroll
    for (int u = 0; u < 8; u++) {
      float4 x4 = xb[u];
      xb[u] = Xq[(u + 8) * 40];   // constant-offset prefetch, 16 steps ahead
      LSTM_STEP(x4.x, x4.y);
      LSTM_STEP(x4.z, x4.w);
    }
    Xq += 8 * 40;
  }
  if (l < 20) ws[OF_HFIN + b * 20 + l] = h;
}

// ---------------- K3: decoder heads + softmax over batch axis -------------------
__global__ __launch_bounds__(256) void k_dec(const float* __restrict__ dec_W,
    const float* __restrict__ dec_b, float* __restrict__ out,
    const float* __restrict__ ws) {
  int wid = blockIdx.x * 4 + (threadIdx.x >> 6);  // (k,v) pair id, 0..1023
  int lane = threadIdx.x & 63;                    // = batch index b
  int k = wid >> 8;
  int v = wid & 255;
  const float* hp = ws + OF_HFIN + lane * 20;
  const float* wp = dec_W + (k * 256 + v) * 20;
  float l = dec_b[k * 256 + v];
#pragma unroll
  for (int jj = 0; jj < 20; jj++) l = fmaf(hp[jj], wp[jj], l);
  float x = l / 0.001f;
  float mx = x;
#pragma unroll
  for (int off = 32; off; off >>= 1) mx = fmaxf(mx, __shfl_xor(mx, off));
  float ex = __expf(x - mx);
  float sm = ex;
#pragma unroll
  for (int off = 32; off; off >>= 1) sm += __shfl_xor(sm, off);
  float p = ex / sm;
  int oidx = (k * 64 + lane) * 256 + v;
  out[oidx] = p;            // probs
  out[65536 + oidx] = l;    // logits
}

// ---------------- K4: byte_e = probs @ addr_emb, encoder, MLP head --------------
__global__ __launch_bounds__(128) void k_freq(const float* __restrict__ addr_emb,
    const float* __restrict__ enc_W, const float* __restrict__ enc_b,
    const float* __restrict__ d1_W, const float* __restrict__ d1_b,
    const float* __restrict__ d2_W, const float* __restrict__ d2_b,
    float* __restrict__ out, const float* __restrict__ ws) {
  __shared__ float be[80];
  __shared__ float fr[60];
  __shared__ float r1[10];
  int b = blockIdx.x;
  int t = threadIdx.x;
  if (t < 80) {
    int k = t / 20, e2 = t % 20;
    const float* pp = out + (k * 64 + b) * 256;        // probs[k,0,b,:]
    const float* ap = addr_emb + (k * 256) * 20 + e2;
    float acc = 0.f;
#pragma unroll 8
    for (int v = 0; v < 256; v++) acc = fmaf(pp[v], ap[v * 20], acc);
    be[t] = acc;   // byte_e[b][k][e2], flat k*20+e2
  }
  __syncthreads();
  if (t < 20) {
    float acc = enc_b[t];
#pragma unroll
    for (int d = 0; d < 80; d++) acc = fmaf(enc_W[t * 80 + d], be[d], acc);
    fr[t] = 1.0f / (1.0f + __expf(-acc));              // fe
  } else if (t < 60) {
    fr[t] = ws[OF_DIST + b * 40 + (t - 20)] * (1.0f / 4096.0f);  // dist_vector
  }
  __syncthreads();
  if (t < 10) {
    float acc = d1_b[t];
#pragma unroll
    for (int d = 0; d < 60; d++) acc = fmaf(d1_W[t * 60 + d], fr[d], acc);
    r1[t] = acc > 0.f ? acc : 0.f;
  }
  __syncthreads();
  if (t < 2) {
    float acc = d2_b[t];
#pragma unroll
    for (int r = 0; r < 10; r++) acc = fmaf(d2_W[t * 10 + r], r1[r], acc);
    out[131072 + t * 64 + b] = acc;
  }
}

extern "C" void kernel_launch(void* const* d_in, const int* in_sizes, int n_in,
                              void* d_out, int out_size, void* d_ws, size_t ws_size,
                              hipStream_t stream) {
  const int*   inp    = (const int*)  d_in[0];
  const float* h0     = (const float*)d_in[1];
  const float* c0     = (const float*)d_in[2];
  const float* pc_emb = (const float*)d_in[3];
  const float* addr_e = (const float*)d_in[4];
  const float* enc_W  = (const float*)d_in[5];
  const float* enc_b  = (const float*)d_in[6];
  const float* W_ih   = (const float*)d_in[7];
  const float* W_hh   = (const float*)d_in[8];
  const float* b_ih   = (const float*)d_in[9];
  const float* b_hh   = (const float*)d_in[10];
  const float* dec_W  = (const float*)d_in[11];
  const float* dec_b  = (const float*)d_in[12];
  const float* d1_W   = (const float*)d_in[13];
  const float* d1_b   = (const float*)d_in[14];
  const float* d2_W   = (const float*)d_in[15];
  const float* d2_b   = (const float*)d_in[16];
  float* out = (float*)d_out;
  float* ws  = (float*)d_ws;

  if (ws_size < WS_NEEDED_FLOATS * sizeof(float)) return;

  hipLaunchKernelGGL(k_init, dim3(31), dim3(256), 0, stream,
                     pc_emb, addr_e, enc_W, b_ih, b_hh, W_ih, ws);
  hipLaunchKernelGGL(k_embed, dim3(4096), dim3(64), 0, stream, inp, enc_b, ws);
  hipLaunchKernelGGL(k_lstm, dim3(64), dim3(64), 0, stream, h0, c0, W_hh, ws);
  hipLaunchKernelGGL(k_dec, dim3(256), dim3(256), 0, stream, dec_W, dec_b, out, ws);
  hipLaunchKernelGGL(k_freq, dim3(64), dim3(128), 0, stream,
                     addr_e, enc_W, enc_b, d1_W, d1_b, d2_W, d2_b, out, ws);
}